// Round 11
// baseline (208.215 us; speedup 1.0000x reference)
//
#include <hip/hip_runtime.h>

// Problem constants
#define Bn 2
#define Mn 25000
#define Nn 100000
#define MK 400000           // Mn*Kn points per batch
#define GN_EPS 1e-5f
#define NEG_BIG (-3.402823466e+38f)
#define LOG2E 1.44269504088896340736f

#define G1 512              // gatherx blocks per batch
#define G2 512              // pass2 blocks per batch

// ws layout (float offsets). No atomics; every region fully written before read.
#define BEFF_OFF 0        // [64]      at_w1@pe_b2 + at_b1
#define B1P_OFF  64       // [2][64]   folded gn1 bias
#define AB1P_OFF 192      // [2][64]   folded gn2 bias: a2*ab1 + c2
#define AB2L_OFF 320      // [64]      ab2 * log2e
#define WF16_OFF 384      // 3*4096 f16: w2, aw2*log2e, Weff    (6144 floats)
#define AW1P_OFF 6528     // [2][4096] f16 folded a2*aw1        (4096 floats)
#define W1F_OFF  10624    // [2][64][8] f16 a1-folded W1, K-pad (512 floats)
#define MSK_OFF  11136    // [2][25024] u16 packed mask         (25024 floats)
#define SP_OFF   36160    // [2][G1][16] gatherx moment partials(16384 floats)
#define YP_OFF   52544    // [2][G2][128] pass2 partials        (131072 floats)
#define YS_OFF   183616   // [2][128] doubles: reduced sums     (512 floats)
#define KXT_OFF  184128   // [2][Nn][4] f32 transposed kx       (800000 floats)
#define QT_OFF   984128   // [2][Mn][4] f32 transposed q        (200000 floats)
#define XF_OFF   1184128  // [2][MK][4] f16 cached local_pattern(1600000 floats)
// total: 2784128 floats ≈ 11.14 MB

typedef _Float16 hf8 __attribute__((ext_vector_type(8)));
typedef _Float16 hf4 __attribute__((ext_vector_type(4)));
typedef _Float16 hf2 __attribute__((ext_vector_type(2)));
typedef float f32x16 __attribute__((ext_vector_type(16)));

__device__ __forceinline__ f32x16 mfma16(hf8 a, hf8 b, f32x16 c) {
    return __builtin_amdgcn_mfma_f32_32x32x16_f16(a, b, c, 0, 0, 0);
}
__device__ __forceinline__ f32x16 splat16(float v) {
    f32x16 x;
#pragma unroll
    for (int r = 0; r < 16; ++r) x[r] = v;
    return x;
}
__device__ __forceinline__ hf8 zero8() {
    hf8 z;
#pragma unroll
    for (int j = 0; j < 8; ++j) z[j] = (_Float16)0.f;
    return z;
}
__device__ __forceinline__ hf2 pkcvt(float a, float b) {
    return __builtin_bit_cast(hf2, __builtin_amdgcn_cvt_pkrtz(a, b));
}
__device__ __forceinline__ hf2 pkrelu(hf2 v) {
    hf2 z; z[0] = (_Float16)0.f; z[1] = (_Float16)0.f;
    return __builtin_elementwise_max(v, z);
}
__device__ __forceinline__ float waveSum(float v) {
#pragma unroll
    for (int s = 32; s; s >>= 1) v += __shfl_down(v, s, 64);
    return v;
}
#define ROWFN(r, lane) (((r) & 3) + 8*((r) >> 2) + 4*((lane) >> 5))

// ---------------- Kernel 0: transpose kx/q to [n][4] ----------------
__global__ __launch_bounds__(256) void prep0_kernel(
    const float* __restrict__ q, const float* __restrict__ kx,
    float* __restrict__ ws)
{
    float4* kxt = (float4*)(ws + KXT_OFF);
    float4* qt  = (float4*)(ws + QT_OFF);
    for (int e = blockIdx.x*256 + threadIdx.x; e < 2*Nn; e += gridDim.x*256) {
        const int b = e / Nn, n = e % Nn;
        float4 v;
        v.x = kx[(b*3+0)*Nn + n]; v.y = kx[(b*3+1)*Nn + n];
        v.z = kx[(b*3+2)*Nn + n]; v.w = 0.f;
        kxt[e] = v;
    }
    for (int e = blockIdx.x*256 + threadIdx.x; e < 2*Mn; e += gridDim.x*256) {
        const int b = e / Mn, m = e % Mn;
        float4 v;
        v.x = q[(b*3+0)*Mn + m]; v.y = q[(b*3+1)*Mn + m];
        v.z = q[(b*3+2)*Mn + m]; v.w = 0.f;
        qt[e] = v;
    }
}

// ---------------- Kernel A: gather once -> x-cache (f16) + packed mask + moments ----------------
__global__ __launch_bounds__(256) void gatherx_kernel(
    const int* __restrict__ idx, const int* __restrict__ mask,
    float* __restrict__ ws)
{
    __shared__ float red[4][16];
    const int b = blockIdx.y;
    const float4* kxt = (const float4*)(ws + KXT_OFF) + (size_t)b*Nn;
    const float4* qt  = (const float4*)(ws + QT_OFF)  + (size_t)b*Mn;
    _Float16* xf = (_Float16*)(ws + XF_OFF);
    unsigned short* m16 = (unsigned short*)(ws + MSK_OFF) + (size_t)b*25024;
    float v[14];
#pragma unroll
    for (int j = 0; j < 14; ++j) v[j] = 0.f;

    for (int i = blockIdx.x*256 + threadIdx.x; i < MK; i += G1*256) {
        const int mm = i >> 4;
        const int id = idx[(size_t)b*MK + i];
        const float4 kv = kxt[id];
        const float4 qv = qt[mm];
        const float ox = kv.x - qv.x, oy = kv.y - qv.y, oz = kv.z - qv.z;
        const float d  = sqrtf(ox*ox + oy*oy + oz*oz);
        const float inv = 1.0f / fmaxf(d, 1e-12f);
        const float x0 = ox*inv, x1 = oy*inv, x2 = oz*inv, x3 = d;

        const hf2 lo = pkcvt(x0, x1);
        const hf2 hi = pkcvt(x2, x3);
        hf4 pk;
        pk[0] = lo[0]; pk[1] = lo[1]; pk[2] = hi[0]; pk[3] = hi[1];
        *(hf4*)&xf[((size_t)b*MK + i)*4] = pk;

        const unsigned long long mb = __ballot(mask[(size_t)b*MK + i] != 0);
        if ((threadIdx.x & 63) == 0)
            *(unsigned long long*)&m16[i >> 4] = mb;

        v[0] += x0; v[1] += x1; v[2] += x2; v[3] += x3;
        v[4] += x0*x0; v[5] += x0*x1; v[6] += x0*x2; v[7] += x0*x3;
        v[8] += x1*x1; v[9] += x1*x2; v[10] += x1*x3;
        v[11] += x2*x2; v[12] += x2*x3; v[13] += x3*x3;
    }
    const int lane = threadIdx.x & 63, wv = threadIdx.x >> 6;
#pragma unroll
    for (int j = 0; j < 14; ++j) v[j] = waveSum(v[j]);
    if (lane == 0) {
#pragma unroll
        for (int j = 0; j < 14; ++j) red[wv][j] = v[j];
    }
    __syncthreads();
    if (threadIdx.x < 14)
        ws[SP_OFF + ((size_t)b*G1 + blockIdx.x)*16 + threadIdx.x] =
            red[0][threadIdx.x] + red[1][threadIdx.x] + red[2][threadIdx.x] + red[3][threadIdx.x];
}

// ---------------- Kernel B: block0: moments -> gn1 fold + beff + ab2 prescale;
//                  blocks 1..16: Weff + f16 weight conversion (data-independent) ----------------
__global__ void prep1_kernel(
    const float* __restrict__ ws_r,
    const float* __restrict__ w1, const float* __restrict__ b1,
    const float* __restrict__ g1, const float* __restrict__ be1,
    const float* __restrict__ w2, const float* __restrict__ pe_b2,
    const float* __restrict__ aw1, const float* __restrict__ ab1,
    const float* __restrict__ aw2, const float* __restrict__ ab2,
    float* __restrict__ ws)
{
    const int t = threadIdx.x;
    _Float16* WF = (_Float16*)(ws + WF16_OFF);

    if (blockIdx.x > 0) {
        // one element per thread: 16 blocks x 256 threads = 4096 elements
        const int e = (blockIdx.x - 1)*256 + t;
        const int o = e >> 6, c = e & 63;
        WF[e]        = (_Float16)w2[e];
        WF[4096 + e] = (_Float16)(aw2[e] * LOG2E);
        float acc = 0.f;
        for (int d = 0; d < 64; ++d) acc = fmaf(aw1[o*64 + d], w2[d*64 + c], acc);
        WF[8192 + e] = (_Float16)acc;
        return;
    }

    __shared__ double S[2][14];
    __shared__ float Eh[2][64], Eq[2][64];

    if (t < 28) {
        const int b = t / 14, j = t % 14;
        const float* p = ws_r + SP_OFF + (size_t)b*G1*16 + j;
        double acc = 0.0;
        for (int g = 0; g < G1; g += 4)
            acc += (double)p[(g+0)*16] + (double)p[(g+1)*16]
                 + (double)p[(g+2)*16] + (double)p[(g+3)*16];
        S[b][j] = acc;
    }
    __syncthreads();

    if (t < 128) {
        const int b = t >> 6, o = t & 63;
        const double inv = 1.0 / (double)MK;
        double mu[4];
#pragma unroll
        for (int c = 0; c < 4; ++c) mu[c] = S[b][c] * inv;
        double m2[4][4];
        {
            const int map[4][4] = {{0,1,2,3},{1,4,5,6},{2,5,7,8},{3,6,8,9}};
#pragma unroll
            for (int c = 0; c < 4; ++c)
#pragma unroll
                for (int c2 = 0; c2 < 4; ++c2)
                    m2[c][c2] = S[b][4 + map[c][c2]] * inv;
        }
        double w[4];
#pragma unroll
        for (int c = 0; c < 4; ++c) w[c] = (double)w1[o*4 + c];
        double s = 0.0, qd = 0.0;
#pragma unroll
        for (int c = 0; c < 4; ++c) {
            s += w[c] * mu[c];
#pragma unroll
            for (int c2 = 0; c2 < 4; ++c2) qd += w[c]*w[c2]*m2[c][c2];
        }
        const double bb = (double)b1[o];
        Eh[b][o] = (float)(s + bb);
        Eq[b][o] = (float)(qd + 2.0*bb*s + bb*bb);
    }
    __syncthreads();
    if (t < 128) {
        const int b = t >> 6, o = t & 63, g = o & ~7;
        float mg = 0.f, qg = 0.f;
#pragma unroll
        for (int j = 0; j < 8; ++j) { mg += Eh[b][g + j]; qg += Eq[b][g + j]; }
        mg *= 0.125f; qg *= 0.125f;
        const float var = fmaxf(qg - mg*mg, 0.f);
        const float a = g1[o] / sqrtf(var + GN_EPS);
        const float c1v = be1[o] - mg*a;
        _Float16* W1F = (_Float16*)(ws + W1F_OFF);
        hf8 wrow;
#pragma unroll
        for (int c = 0; c < 4; ++c) wrow[c] = (_Float16)(a * w1[o*4 + c]);
#pragma unroll
        for (int c = 4; c < 8; ++c) wrow[c] = (_Float16)0.f;
        *(hf8*)&W1F[(b*64 + o)*8] = wrow;
        ws[B1P_OFF + b*64 + o] = fmaf(a, b1[o], c1v);
    }
    if (t < 64) {
        float acc = ab1[t];
        for (int d = 0; d < 64; ++d) acc = fmaf(aw1[t*64 + d], pe_b2[d], acc);
        ws[BEFF_OFF + t] = acc;
    } else if (t < 128) {
        ws[AB2L_OFF + (t - 64)] = ab2[t - 64] * LOG2E;
    }
}

// ---------------- Kernel C: two-tile Σy, Σy² (y = Weff@r1), all-MFMA ----------------
__global__ __launch_bounds__(256, 3) void pass2_kernel(
    const float* __restrict__ cws, float* __restrict__ ws)
{
    __shared__ __align__(16) _Float16 Xs[8][32][72];   // 36.9 KB
    const int b = blockIdx.y;
    const int tid = threadIdx.x, lane = tid & 63, wv = tid >> 6;
    const int colA = lane & 31;
    const int klo = (lane >> 5) * 8;
    const _Float16* xf  = (const _Float16*)(cws + XF_OFF);
    const _Float16* WFe = (const _Float16*)(cws + WF16_OFF) + 8192;  // Weff
    const _Float16* W1F = (const _Float16*)(cws + W1F_OFF);

    hf8 BW[2][4];
#pragma unroll
    for (int jc = 0; jc < 2; ++jc)
#pragma unroll
        for (int ks = 0; ks < 4; ++ks)
            BW[jc][ks] = *(const hf8*)&WFe[(2*colA + jc)*64 + 16*ks + klo];
    hf8 BX[2];
    if (klo == 0) {
        BX[0] = *(const hf8*)&W1F[(b*64 + 2*colA)*8];
        BX[1] = *(const hf8*)&W1F[(b*64 + 2*colA + 1)*8];
    } else { BX[0] = zero8(); BX[1] = zero8(); }
    const float bias0 = cws[B1P_OFF + b*64 + 2*colA];
    const float bias1 = cws[B1P_OFF + b*64 + 2*colA + 1];

    float sh[2] = {0.f, 0.f}, sq[2] = {0.f, 0.f};

    for (int base = blockIdx.x * 256; base < MK; base += G2 * 256) {
        const int p0 = base + 64*wv;
        const int p1 = p0 + 32;        // MK % 32 == 0: tiles are whole or absent
        hf8 ax0 = zero8(), ax1 = zero8();
        if (klo == 0) {
            if (p0 < MK) {
                hf4 xv = *(const hf4*)&xf[((size_t)b*MK + p0 + colA)*4];
#pragma unroll
                for (int j = 0; j < 4; ++j) ax0[j] = xv[j];
            }
            if (p1 < MK) {
                hf4 xv = *(const hf4*)&xf[((size_t)b*MK + p1 + colA)*4];
#pragma unroll
                for (int j = 0; j < 4; ++j) ax1[j] = xv[j];
            }
        }
        // r1 GEMM, 4 chains, BX shared across tiles
        f32x16 r00 = splat16(bias0), r01 = splat16(bias1);
        f32x16 r10 = r00, r11 = r01;
        r00 = mfma16(ax0, BX[0], r00);
        r01 = mfma16(ax0, BX[1], r01);
        r10 = mfma16(ax1, BX[0], r10);
        r11 = mfma16(ax1, BX[1], r11);
#pragma unroll
        for (int r = 0; r < 16; ++r) {
            const int row = ROWFN(r, lane);
            *(hf2*)&Xs[2*wv    ][row][2*colA] = pkrelu(pkcvt(r00[r], r01[r]));
            *(hf2*)&Xs[2*wv + 1][row][2*colA] = pkrelu(pkcvt(r10[r], r11[r]));
        }
        // Weff GEMM, 4 chains, BW shared across tiles
        hf8 A0[4], A1[4];
#pragma unroll
        for (int ks = 0; ks < 4; ++ks) {
            A0[ks] = *(const hf8*)&Xs[2*wv    ][colA][16*ks + klo];
            A1[ks] = *(const hf8*)&Xs[2*wv + 1][colA][16*ks + klo];
        }
#pragma unroll
        for (int jc = 0; jc < 2; ++jc) {
            f32x16 C0 = splat16(0.f), C1 = splat16(0.f);
#pragma unroll
            for (int ks = 0; ks < 4; ++ks) {
                C0 = mfma16(A0[ks], BW[jc][ks], C0);
                C1 = mfma16(A1[ks], BW[jc][ks], C1);
            }
#pragma unroll
            for (int r = 0; r < 16; ++r) {
                sh[jc] += C0[r] + C1[r];
                sq[jc] = fmaf(C0[r], C0[r], sq[jc]);
                sq[jc] = fmaf(C1[r], C1[r], sq[jc]);
            }
        }
    }

#pragma unroll
    for (int jc = 0; jc < 2; ++jc) {
        sh[jc] += __shfl_xor(sh[jc], 32, 64);
        sq[jc] += __shfl_xor(sq[jc], 32, 64);
    }
    __syncthreads();
    float* red = (float*)Xs;   // [4][128]
    if (lane < 32) {
#pragma unroll
        for (int jc = 0; jc < 2; ++jc) {
            red[wv*128 +      2*colA + jc] = sh[jc];
            red[wv*128 + 64 + 2*colA + jc] = sq[jc];
        }
    }
    __syncthreads();
    if (tid < 128) {
        const float v = red[tid] + red[128 + tid] + red[256 + tid] + red[384 + tid];
        ws[YP_OFF + ((size_t)b*G2 + blockIdx.x)*128 + tid] = v;
    }
}

// ---------------- Kernel D1: parallel reduce of pass2 partials (one block per output) ----------------
__global__ __launch_bounds__(64) void prep2a_kernel(
    const float* __restrict__ ws_r, float* __restrict__ ws)
{
    const int o2 = blockIdx.x;            // [0,256): b = o2>>7, i = o2&127
    const int b = o2 >> 7, i = o2 & 127;
    const float* p = ws_r + YP_OFF + (size_t)b*G2*128 + i;
    double acc = 0.0;
    for (int g = threadIdx.x; g < G2; g += 64) acc += (double)p[(size_t)g*128];
#pragma unroll
    for (int s = 32; s; s >>= 1) acc += __shfl_down(acc, s, 64);
    if (threadIdx.x == 0) ((double*)(ws + YS_OFF))[o2] = acc;
}

// ---------------- Kernel D2: gn2 coeffs + fold into aw1/ab1 ----------------
__global__ void prep2b_kernel(const float* __restrict__ ws_r,
                              const float* __restrict__ g2, const float* __restrict__ be2,
                              const float* __restrict__ aw1, const float* __restrict__ ab1,
                              float* __restrict__ ws)
{
    __shared__ float EH[2][64], EQ[2][64];
    __shared__ float A2s[2][64];
    const int t = threadIdx.x;   // 256
    const double* YS = (const double*)(ws_r + YS_OFF);
    if (t < 128) {
        const int b = t >> 6, o = t & 63;
        const double invMK = 1.0 / (double)MK;
        const double my = YS[b*128 + o] * invMK;
        const double qy = YS[b*128 + 64 + o] * invMK;
        const double beff = (double)ws_r[BEFF_OFF + o];
        EH[b][o] = (float)(my + beff);
        EQ[b][o] = (float)(qy + 2.0*beff*my + beff*beff);
    }
    __syncthreads();
    if (t < 128) {
        const int b = t >> 6, o = t & 63, g = o & ~7;
        float mg = 0.f, qg = 0.f;
#pragma unroll
        for (int j = 0; j < 8; ++j) { mg += EH[b][g + j]; qg += EQ[b][g + j]; }
        mg *= 0.125f; qg *= 0.125f;
        const float var = fmaxf(qg - mg*mg, 0.f);
        const float a = g2[o] / sqrtf(var + GN_EPS);
        A2s[b][o] = a;
        ws[AB1P_OFF + b*64 + o] = fmaf(a, ab1[o], be2[o] - mg*a);
    }
    __syncthreads();
    _Float16* AW1P = (_Float16*)(ws + AW1P_OFF);
    for (int e = t; e < 8192; e += 256) {
        const int b = e >> 12, oc = e & 4095, o = oc >> 6;
        AW1P[e] = (_Float16)(A2s[b][o] * aw1[oc]);
    }
}

// ---------------- Kernel E: two-tile all-MFMA forward (64 pts/wave, B-fragments reused) ----------------
__global__ __launch_bounds__(256, 3) void pass3_kernel(
    const float* __restrict__ b2,
    const float* __restrict__ cws, float* __restrict__ out)
{
    __shared__ __align__(16) _Float16 Xs[8][32][72];   // [2*wv+t][row][col] 36.9 KB
    float* O = (float*)Xs;                             // aliased after barrier: [64][17]

    const int b = blockIdx.y;
    const int base = blockIdx.x * 256;                 // grid.x = 1563; last block partial
    const int tid = threadIdx.x;
    const int lane = tid & 63, wv = tid >> 6;
    const int colA = lane & 31;
    const int klo = (lane >> 5) * 8;

    const _Float16* xf   = (const _Float16*)(cws + XF_OFF);
    const _Float16* WF   = (const _Float16*)(cws + WF16_OFF);
    const _Float16* AW1P = (const _Float16*)(cws + AW1P_OFF) + (size_t)b*4096;
    const _Float16* W1F  = (const _Float16*)(cws + W1F_OFF);
    const unsigned short* m16 = (const unsigned short*)(cws + MSK_OFF) + (size_t)b*25024;

    int pt0[2];
    pt0[0] = base + 64*wv;
    pt0[1] = base + 64*wv + 32;
    unsigned mb[2];
#pragma unroll
    for (int t = 0; t < 2; ++t)
        mb[t] = (pt0[t] < MK) ? *(const unsigned*)(m16 + (pt0[t] >> 4)) : 0u;
    const unsigned mbs0 = __builtin_amdgcn_readfirstlane(mb[0]);
    const unsigned mbs1 = __builtin_amdgcn_readfirstlane(mb[1]);

    // ---- r1 via MFMA from cached x (both tiles; BX shared) ----
    {
        hf8 BX0, BX1;
        if (klo == 0) {
            BX0 = *(const hf8*)&W1F[(b*64 + 2*colA)*8];
            BX1 = *(const hf8*)&W1F[(b*64 + 2*colA + 1)*8];
        } else { BX0 = zero8(); BX1 = zero8(); }
        const float bias0 = cws[B1P_OFF + b*64 + 2*colA];
        const float bias1 = cws[B1P_OFF + b*64 + 2*colA + 1];
#pragma unroll
        for (int t = 0; t < 2; ++t) {
            hf8 ax = zero8();
            if (klo == 0 && pt0[t] < MK) {
                hf4 xv = *(const hf4*)&xf[((size_t)b*MK + pt0[t] + colA)*4];
#pragma unroll
                for (int j = 0; j < 4; ++j) ax[j] = xv[j];
            }
            f32x16 r0 = splat16(bias0), r1t = splat16(bias1);
            r0  = mfma16(ax, BX0, r0);
            r1t = mfma16(ax, BX1, r1t);
#pragma unroll
            for (int r = 0; r < 16; ++r) {
                const int row = ROWFN(r, lane);
                *(hf2*)&Xs[2*wv + t][row][2*colA] = pkrelu(pkcvt(r0[r], r1t[r]));
            }
            // mask bias into pad cols [64..71]: full 8-half write (no uninit LDS)
            if (lane < 32) {
                hf8 pad = zero8();
                pad[0] = ((mb[t] >> lane) & 1u) ? (_Float16)0.f : (_Float16)(-60000.f);
                *(hf8*)&Xs[2*wv + t][lane][64] = pad;
            }
        }
    }

    // ---- GEMM1: pe = r1 @ w2^T + b2 (B reused across tiles) ----
    hf2 pe_pk[2][16];   // packed pe kept for softmax (32 VGPRs)
    {
        f32x16 p00 = splat16(b2[2*colA]);
        f32x16 p01 = splat16(b2[2*colA + 1]);
        f32x16 p10 = p00, p11 = p01;
#pragma unroll
        for (int ks = 0; ks < 4; ++ks) {
            const int off = 16*ks + klo;
            hf8 a0  = *(const hf8*)&Xs[2*wv    ][colA][off];
            hf8 a1  = *(const hf8*)&Xs[2*wv + 1][colA][off];
            hf8 b0f = *(const hf8*)&WF[(2*colA)*64 + off];
            hf8 b1f = *(const hf8*)&WF[(2*colA + 1)*64 + off];
            p00 = mfma16(a0, b0f, p00);
            p01 = mfma16(a0, b1f, p01);
            p10 = mfma16(a1, b0f, p10);
            p11 = mfma16(a1, b1f, p11);
        }
#pragma unroll
        for (int r = 0; r < 16; ++r) {
            const int row = ROWFN(r, lane);
            pe_pk[0][r] = pkcvt(p00[r], p01[r]);
            pe_pk[1][r] = pkcvt(p10[r], p11[r]);
            *(hf2*)&Xs[2*wv    ][row][2*colA] = pe_pk[0][r];
            *(hf2*)&Xs[2*wv + 1][row][2*colA] = pe_pk[1][r];
        }
    }

    // ---- GEMM2: r2 = relu(pe @ (a2*aw1)^T + ab1') ----
    {
        f32x16 h00 = splat16(cws[AB1P_OFF + b*64 + 2*colA]);
        f32x16 h01 = splat16(cws[AB1P_OFF + b*64 + 2*colA + 1]);
        f32x16 h10 = h00, h11 = h01;
#pragma unroll
        for (int ks = 0; ks < 4; ++ks) {
            const int off = 16*ks + klo;
            hf8 a0  = *(const hf8*)&Xs[2*wv    ][colA][off];
            hf8 a1  = *(const hf8*)&Xs[2*wv + 1][colA][off];
            hf8 b0f = *(const hf8*)&AW1P[(2*colA)*64 + off];
            hf8 b1f = *(const hf8*)&AW1P[(2*colA + 1)*64 + off];
            h00 = mfma16(a0, b0f, h00);
            h01 = mfma16(a0, b1f, h01);
            h10 = mfma16(a1, b0f, h10);
            h11 = mfma16(a1, b1f, h11);
        }
#pragma unroll
        for (int r = 0; r < 16; ++r) {
            const int row = ROWFN(r, lane);
            *(hf2*)&Xs[2*wv    ][row][2*colA] = pkrelu(pkcvt(h00[r], h01[r]));
            *(hf2*)&Xs[2*wv + 1][row][2*colA] = pkrelu(pkcvt(h10[r], h11[r]));
        }
    }

    // ---- GEMM3: logits(log2) = r2 @ (aw2*log2e)^T + ab2*log2e + mask rank-1 ----
    f32x16 l00 = splat16(cws[AB2L_OFF + 2*colA]);
    f32x16 l01 = splat16(cws[AB2L_OFF + 2*colA + 1]);
    f32x16 l10 = l00, l11 = l01;
#pragma unroll
    for (int ks = 0; ks < 4; ++ks) {
        const int off = 16*ks + klo;
        hf8 a0  = *(const hf8*)&Xs[2*wv    ][colA][off];
        hf8 a1  = *(const hf8*)&Xs[2*wv + 1][colA][off];
        hf8 b0f = *(const hf8*)&WF[4096 + (2*colA)*64 + off];
        hf8 b1f = *(const hf8*)&WF[4096 + (2*colA + 1)*64 + off];
        l00 = mfma16(a0, b0f, l00);
        l01 = mfma16(a0, b1f, l01);
        l10 = mfma16(a1, b0f, l10);
        l11 = mfma16(a1, b1f, l11);
    }
    {
        hf8 b5 = zero8();
        if (klo == 0) b5[0] = (_Float16)1.f;
        hf8 a50 = zero8(), a51 = zero8();
        if (klo == 0) {
            a50 = *(const hf8*)&Xs[2*wv    ][colA][64];
            a51 = *(const hf8*)&Xs[2*wv + 1][colA][64];
        }
        l00 = mfma16(a50, b5, l00);
        l01 = mfma16(a50, b5, l01);
        l10 = mfma16(a51, b5, l10);
        l11 = mfma16(a51, b5, l11);
    }

    __syncthreads();   // all Xs reads done; O may alias Xs

    // ---- softmax over K=16 (exp2 domain) + weighted pe sum ----
    {
        auto softmax_tile = [&](const f32x16& lg, const hf2* pp, unsigned mbst,
                                int t, int j) {
#pragma unroll
            for (int mh = 0; mh < 2; ++mh) {
                float mx = lg[8*mh];
#pragma unroll
                for (int rr = 1; rr < 8; ++rr) mx = fmaxf(mx, lg[8*mh + rr]);
                mx = fmaxf(mx, __shfl_xor(mx, 32, 64));
                float se, sw = 0.f;
                if (((mbst >> (16*mh)) & 0xFFFFu) != 0u) {
                    se = 0.f;
#pragma unroll
                    for (int rr = 0; rr < 8; ++rr) {
                        const float e = exp2f(lg[8*mh + rr] - mx);
                        se += e;
                        sw = fmaf(e, (float)pp[8*mh + rr][j], sw);
                    }
                } else {
                    se = 8.f;
#pragma unroll
                    for (int rr = 0; rr < 8; ++rr) sw += (float)pp[8*mh + rr][j];
                }
                se += __shfl_xor(se, 32, 64);
                sw += __shfl_xor(sw, 32, 64);
                if (lane < 32)
                    O[(2*lane + j)*17 + (4*wv + 2*t + mh)] = sw * __builtin_amdgcn_rcpf(se);
            }
        };
        softmax_tile(l00, pe_pk[0], mbs0, 0, 0);
        softmax_tile(l01, pe_pk[0], mbs0, 0, 1);
        softmax_tile(l10, pe_pk[1], mbs1, 1, 0);
        softmax_tile(l11, pe_pk[1], mbs1, 1, 1);
    }
    __syncthreads();

    {   // 64 ch x 16 m per block, one float4 per thread
        const int o = tid >> 2, mq = (tid & 3) * 4;
        const int m0 = blockIdx.x * 16;
        if (m0 + mq < Mn) {
            float4 v;
            v.x = O[o*17 + mq];     v.y = O[o*17 + mq + 1];
            v.z = O[o*17 + mq + 2]; v.w = O[o*17 + mq + 3];
            *(float4*)&out[((size_t)b*64 + o)*Mn + m0 + mq] = v;
        }
    }
}

extern "C" void kernel_launch(void* const* d_in, const int* in_sizes, int n_in,
                              void* d_out, int out_size, void* d_ws, size_t ws_size,
                              hipStream_t stream) {
    (void)in_sizes; (void)n_in; (void)out_size; (void)ws_size;
    const float* q    = (const float*)d_in[0];
    const float* kx   = (const float*)d_in[1];
    const int*   idx  = (const int*)  d_in[2];
    const int*   mask = (const int*)  d_in[3];
    const float* w1   = (const float*)d_in[4];
    const float* b1   = (const float*)d_in[5];
    const float* g1   = (const float*)d_in[6];
    const float* be1  = (const float*)d_in[7];
    const float* w2   = (const float*)d_in[8];
    const float* b2   = (const float*)d_in[9];
    const float* aw1  = (const float*)d_in[10];
    const float* ab1  = (const float*)d_in[11];
    const float* g2   = (const float*)d_in[12];
    const float* be2  = (const float*)d_in[13];
    const float* aw2  = (const float*)d_in[14];
    const float* ab2  = (const float*)d_in[15];
    float* out = (float*)d_out;
    float* ws  = (float*)d_ws;

    prep0_kernel<<<256, 256, 0, stream>>>(q, kx, ws);
    gatherx_kernel<<<dim3(G1, Bn), 256, 0, stream>>>(idx, mask, ws);
    prep1_kernel<<<17, 256, 0, stream>>>(ws, w1, b1, g1, be1, w2, b2, aw1, ab1, aw2, ab2, ws);
    pass2_kernel<<<dim3(G2, Bn), 256, 0, stream>>>(ws, ws);
    prep2a_kernel<<<256, 64, 0, stream>>>(ws, ws);
    prep2b_kernel<<<1, 256, 0, stream>>>(ws, g2, be2, aw1, ab1, ws);
    pass3_kernel<<<dim3((MK + 255)/256, Bn), 256, 0, stream>>>(b2, ws, out);
}

// Round 12
// 197.552 us; speedup vs baseline: 1.0540x; 1.0540x over previous
//
#include <hip/hip_runtime.h>

// Problem constants
#define Bn 2
#define Mn 25000
#define Nn 100000
#define MK 400000           // Mn*Kn points per batch
#define GN_EPS 1e-5f
#define NEG_BIG (-3.402823466e+38f)
#define LOG2E 1.44269504088896340736f

#define G1 256              // gatherx blocks per batch (512-pt tiles)
#define G2 512              // pass2 blocks per batch

// ws layout (float offsets). No atomics; every region fully written before read.
#define BEFF_OFF 0        // [64]      at_w1@pe_b2 + at_b1
#define B1P_OFF  64       // [2][64]   folded gn1 bias
#define AB1P_OFF 192      // [2][64]   folded gn2 bias: a2*ab1 + c2
#define AB2L_OFF 320      // [64]      ab2 * log2e
#define WF16_OFF 384      // 3*4096 f16: w2, aw2*log2e, Weff    (6144 floats)
#define AW1P_OFF 6528     // [2][4096] f16 folded a2*aw1        (4096 floats)
#define W1F_OFF  10624    // [2][64][8] f16 a1-folded W1, K-pad (512 floats)
#define MSK_OFF  11136    // [2][25024] u16 packed mask         (25024 floats)
#define SP_OFF   36160    // [2][G1][16] gatherx moment partials(8192 used)
#define YP_OFF   52544    // [2][G2][128] pass2 partials        (131072 floats)
#define YS_OFF   183616   // [2][128] doubles: reduced sums     (512 floats)
#define KXT_OFF  184128   // [2][Nn][4] f32 transposed kx       (800000 floats)
#define QT_OFF   984128   // [2][Mn][4] f32 transposed q        (200000 floats)
#define XF_OFF   1184128  // [2][MK][4] f16 cached local_pattern(1600000 floats)
// total: 2784128 floats ≈ 11.14 MB

typedef _Float16 hf8 __attribute__((ext_vector_type(8)));
typedef _Float16 hf4 __attribute__((ext_vector_type(4)));
typedef _Float16 hf2 __attribute__((ext_vector_type(2)));
typedef float f32x16 __attribute__((ext_vector_type(16)));

__device__ __forceinline__ f32x16 mfma16(hf8 a, hf8 b, f32x16 c) {
    return __builtin_amdgcn_mfma_f32_32x32x16_f16(a, b, c, 0, 0, 0);
}
__device__ __forceinline__ f32x16 splat16(float v) {
    f32x16 x;
#pragma unroll
    for (int r = 0; r < 16; ++r) x[r] = v;
    return x;
}
__device__ __forceinline__ hf8 zero8() {
    hf8 z;
#pragma unroll
    for (int j = 0; j < 8; ++j) z[j] = (_Float16)0.f;
    return z;
}
__device__ __forceinline__ hf2 pkcvt(float a, float b) {
    return __builtin_bit_cast(hf2, __builtin_amdgcn_cvt_pkrtz(a, b));
}
__device__ __forceinline__ hf2 pkrelu(hf2 v) {
    hf2 z; z[0] = (_Float16)0.f; z[1] = (_Float16)0.f;
    return __builtin_elementwise_max(v, z);
}
__device__ __forceinline__ float waveSum(float v) {
#pragma unroll
    for (int s = 32; s; s >>= 1) v += __shfl_down(v, s, 64);
    return v;
}
#define ROWFN(r, lane) (((r) & 3) + 8*((r) >> 2) + 4*((lane) >> 5))

// ---------------- Kernel 0: transpose kx/q to [n][4] ----------------
__global__ __launch_bounds__(256) void prep0_kernel(
    const float* __restrict__ q, const float* __restrict__ kx,
    float* __restrict__ ws)
{
    float4* kxt = (float4*)(ws + KXT_OFF);
    float4* qt  = (float4*)(ws + QT_OFF);
    for (int e = blockIdx.x*256 + threadIdx.x; e < 2*Nn; e += gridDim.x*256) {
        const int b = e / Nn, n = e % Nn;
        float4 v;
        v.x = kx[(b*3+0)*Nn + n]; v.y = kx[(b*3+1)*Nn + n];
        v.z = kx[(b*3+2)*Nn + n]; v.w = 0.f;
        kxt[e] = v;
    }
    for (int e = blockIdx.x*256 + threadIdx.x; e < 2*Mn; e += gridDim.x*256) {
        const int b = e / Mn, m = e % Mn;
        float4 v;
        v.x = q[(b*3+0)*Mn + m]; v.y = q[(b*3+1)*Mn + m];
        v.z = q[(b*3+2)*Mn + m]; v.w = 0.f;
        qt[e] = v;
    }
}

// ---------------- Kernel A: gather (2 pts/thread, loads batched) ----------------
__global__ __launch_bounds__(256) void gatherx_kernel(
    const int* __restrict__ idx, const int* __restrict__ mask,
    float* __restrict__ ws)
{
    __shared__ float red[4][16];
    const int b = blockIdx.y;
    const float4* kxt = (const float4*)(ws + KXT_OFF) + (size_t)b*Nn;
    const float4* qt  = (const float4*)(ws + QT_OFF)  + (size_t)b*Mn;
    _Float16* xf = (_Float16*)(ws + XF_OFF);
    unsigned short* m16 = (unsigned short*)(ws + MSK_OFF) + (size_t)b*25024;
    float v[14];
#pragma unroll
    for (int j = 0; j < 14; ++j) v[j] = 0.f;

    for (int base = blockIdx.x*512; base < MK; base += G1*512) {
        const int i0 = base + threadIdx.x;
        const int i1 = i0 + 256;
        const bool v0 = (i0 < MK), v1 = (i1 < MK);   // MK%256==0: wave-uniform

        // ---- issue ALL loads before any compute/store (two chains in flight) ----
        int id0 = 0, id1 = 0, mk0 = 0, mk1 = 0;
        if (v0) { id0 = idx[(size_t)b*MK + i0]; mk0 = mask[(size_t)b*MK + i0]; }
        if (v1) { id1 = idx[(size_t)b*MK + i1]; mk1 = mask[(size_t)b*MK + i1]; }
        float4 kv0, kv1, qv0, qv1;
        if (v0) { kv0 = kxt[id0]; qv0 = qt[i0 >> 4]; }
        if (v1) { kv1 = kxt[id1]; qv1 = qt[i1 >> 4]; }

#pragma unroll
        for (int h = 0; h < 2; ++h) {
            const bool ok = h ? v1 : v0;
            const int i = h ? i1 : i0;
            const float4 kv = h ? kv1 : kv0;
            const float4 qv = h ? qv1 : qv0;
            const int mk = h ? mk1 : mk0;
            float x0 = 0.f, x1 = 0.f, x2 = 0.f, x3 = 0.f;
            if (ok) {
                const float ox = kv.x - qv.x, oy = kv.y - qv.y, oz = kv.z - qv.z;
                const float d  = sqrtf(ox*ox + oy*oy + oz*oz);
                const float inv = 1.0f / fmaxf(d, 1e-12f);
                x0 = ox*inv; x1 = oy*inv; x2 = oz*inv; x3 = d;

                const hf2 lo = pkcvt(x0, x1);
                const hf2 hi = pkcvt(x2, x3);
                hf4 pk;
                pk[0] = lo[0]; pk[1] = lo[1]; pk[2] = hi[0]; pk[3] = hi[1];
                *(hf4*)&xf[((size_t)b*MK + i)*4] = pk;
            }
            const unsigned long long mb = __ballot(ok && (mk != 0));
            if (ok && (threadIdx.x & 63) == 0)
                *(unsigned long long*)&m16[i >> 4] = mb;

            v[0] += x0; v[1] += x1; v[2] += x2; v[3] += x3;
            v[4] += x0*x0; v[5] += x0*x1; v[6] += x0*x2; v[7] += x0*x3;
            v[8] += x1*x1; v[9] += x1*x2; v[10] += x1*x3;
            v[11] += x2*x2; v[12] += x2*x3; v[13] += x3*x3;
        }
    }
    const int lane = threadIdx.x & 63, wv = threadIdx.x >> 6;
#pragma unroll
    for (int j = 0; j < 14; ++j) v[j] = waveSum(v[j]);
    if (lane == 0) {
#pragma unroll
        for (int j = 0; j < 14; ++j) red[wv][j] = v[j];
    }
    __syncthreads();
    if (threadIdx.x < 14)
        ws[SP_OFF + ((size_t)b*G1 + blockIdx.x)*16 + threadIdx.x] =
            red[0][threadIdx.x] + red[1][threadIdx.x] + red[2][threadIdx.x] + red[3][threadIdx.x];
}

// ---------------- Kernel B: block0: moments -> gn1 fold + beff + ab2 prescale;
//                  blocks 1..16: Weff + f16 weight conversion (data-independent) ----------------
__global__ void prep1_kernel(
    const float* __restrict__ ws_r,
    const float* __restrict__ w1, const float* __restrict__ b1,
    const float* __restrict__ g1, const float* __restrict__ be1,
    const float* __restrict__ w2, const float* __restrict__ pe_b2,
    const float* __restrict__ aw1, const float* __restrict__ ab1,
    const float* __restrict__ aw2, const float* __restrict__ ab2,
    float* __restrict__ ws)
{
    const int t = threadIdx.x;
    _Float16* WF = (_Float16*)(ws + WF16_OFF);

    if (blockIdx.x > 0) {
        const int e = (blockIdx.x - 1)*256 + t;
        const int o = e >> 6, c = e & 63;
        WF[e]        = (_Float16)w2[e];
        WF[4096 + e] = (_Float16)(aw2[e] * LOG2E);
        float acc = 0.f;
        for (int d = 0; d < 64; ++d) acc = fmaf(aw1[o*64 + d], w2[d*64 + c], acc);
        WF[8192 + e] = (_Float16)acc;
        return;
    }

    __shared__ double S[2][14];
    __shared__ float Eh[2][64], Eq[2][64];

    if (t < 28) {
        const int b = t / 14, j = t % 14;
        const float* p = ws_r + SP_OFF + (size_t)b*G1*16 + j;
        double acc = 0.0;
        for (int g = 0; g < G1; g += 4)
            acc += (double)p[(g+0)*16] + (double)p[(g+1)*16]
                 + (double)p[(g+2)*16] + (double)p[(g+3)*16];
        S[b][j] = acc;
    }
    __syncthreads();

    if (t < 128) {
        const int b = t >> 6, o = t & 63;
        const double inv = 1.0 / (double)MK;
        double mu[4];
#pragma unroll
        for (int c = 0; c < 4; ++c) mu[c] = S[b][c] * inv;
        double m2[4][4];
        {
            const int map[4][4] = {{0,1,2,3},{1,4,5,6},{2,5,7,8},{3,6,8,9}};
#pragma unroll
            for (int c = 0; c < 4; ++c)
#pragma unroll
                for (int c2 = 0; c2 < 4; ++c2)
                    m2[c][c2] = S[b][4 + map[c][c2]] * inv;
        }
        double w[4];
#pragma unroll
        for (int c = 0; c < 4; ++c) w[c] = (double)w1[o*4 + c];
        double s = 0.0, qd = 0.0;
#pragma unroll
        for (int c = 0; c < 4; ++c) {
            s += w[c] * mu[c];
#pragma unroll
            for (int c2 = 0; c2 < 4; ++c2) qd += w[c]*w[c2]*m2[c][c2];
        }
        const double bb = (double)b1[o];
        Eh[b][o] = (float)(s + bb);
        Eq[b][o] = (float)(qd + 2.0*bb*s + bb*bb);
    }
    __syncthreads();
    if (t < 128) {
        const int b = t >> 6, o = t & 63, g = o & ~7;
        float mg = 0.f, qg = 0.f;
#pragma unroll
        for (int j = 0; j < 8; ++j) { mg += Eh[b][g + j]; qg += Eq[b][g + j]; }
        mg *= 0.125f; qg *= 0.125f;
        const float var = fmaxf(qg - mg*mg, 0.f);
        const float a = g1[o] / sqrtf(var + GN_EPS);
        const float c1v = be1[o] - mg*a;
        _Float16* W1F = (_Float16*)(ws + W1F_OFF);
        hf8 wrow;
#pragma unroll
        for (int c = 0; c < 4; ++c) wrow[c] = (_Float16)(a * w1[o*4 + c]);
#pragma unroll
        for (int c = 4; c < 8; ++c) wrow[c] = (_Float16)0.f;
        *(hf8*)&W1F[(b*64 + o)*8] = wrow;
        ws[B1P_OFF + b*64 + o] = fmaf(a, b1[o], c1v);
    }
    if (t < 64) {
        float acc = ab1[t];
        for (int d = 0; d < 64; ++d) acc = fmaf(aw1[t*64 + d], pe_b2[d], acc);
        ws[BEFF_OFF + t] = acc;
    } else if (t < 128) {
        ws[AB2L_OFF + (t - 64)] = ab2[t - 64] * LOG2E;
    }
}

// ---------------- Kernel C: Σy, Σy² (y = Weff@r1), all-MFMA (R10 version) ----------------
__global__ __launch_bounds__(256, 4) void pass2_kernel(
    const float* __restrict__ cws, float* __restrict__ ws)
{
    __shared__ __align__(16) _Float16 Xs[4][32][72];
    const int b = blockIdx.y;
    const int tid = threadIdx.x, lane = tid & 63, wv = tid >> 6;
    const int colA = lane & 31;
    const int klo = (lane >> 5) * 8;
    const _Float16* xf  = (const _Float16*)(cws + XF_OFF);
    const _Float16* WFe = (const _Float16*)(cws + WF16_OFF) + 8192;  // Weff
    const _Float16* W1F = (const _Float16*)(cws + W1F_OFF);

    hf8 BW[2][4];
#pragma unroll
    for (int jc = 0; jc < 2; ++jc)
#pragma unroll
        for (int ks = 0; ks < 4; ++ks)
            BW[jc][ks] = *(const hf8*)&WFe[(2*colA + jc)*64 + 16*ks + klo];
    hf8 BX[2];
    if (klo == 0) {
        BX[0] = *(const hf8*)&W1F[(b*64 + 2*colA)*8];
        BX[1] = *(const hf8*)&W1F[(b*64 + 2*colA + 1)*8];
    } else { BX[0] = zero8(); BX[1] = zero8(); }
    const float bias0 = cws[B1P_OFF + b*64 + 2*colA];
    const float bias1 = cws[B1P_OFF + b*64 + 2*colA + 1];

    float sh[2] = {0.f, 0.f}, sq[2] = {0.f, 0.f};

    for (int base = blockIdx.x * 128; base < MK; base += G2 * 128) {
        const int pt0 = base + 32*wv;
        hf8 ax = zero8();
        if (klo == 0) {
            hf4 xv = *(const hf4*)&xf[((size_t)b*MK + pt0 + colA)*4];
#pragma unroll
            for (int j = 0; j < 4; ++j) ax[j] = xv[j];
        }
        f32x16 r0 = splat16(bias0), r1t = splat16(bias1);
        r0  = mfma16(ax, BX[0], r0);
        r1t = mfma16(ax, BX[1], r1t);
#pragma unroll
        for (int r = 0; r < 16; ++r) {
            const int row = ROWFN(r, lane);
            *(hf2*)&Xs[wv][row][2*colA] = pkrelu(pkcvt(r0[r], r1t[r]));
        }
        hf8 A[4];
#pragma unroll
        for (int ks = 0; ks < 4; ++ks)
            A[ks] = *(const hf8*)&Xs[wv][colA][16*ks + klo];
#pragma unroll
        for (int jc = 0; jc < 2; ++jc) {
            f32x16 C = splat16(0.f);
#pragma unroll
            for (int ks = 0; ks < 4; ++ks) C = mfma16(A[ks], BW[jc][ks], C);
#pragma unroll
            for (int r = 0; r < 16; ++r) {
                const float vy = C[r];
                sh[jc] += vy;
                sq[jc] = fmaf(vy, vy, sq[jc]);
            }
        }
    }

#pragma unroll
    for (int jc = 0; jc < 2; ++jc) {
        sh[jc] += __shfl_xor(sh[jc], 32, 64);
        sq[jc] += __shfl_xor(sq[jc], 32, 64);
    }
    __syncthreads();
    float* red = (float*)Xs;   // [4][128]
    if (lane < 32) {
#pragma unroll
        for (int jc = 0; jc < 2; ++jc) {
            red[wv*128 +      2*colA + jc] = sh[jc];
            red[wv*128 + 64 + 2*colA + jc] = sq[jc];
        }
    }
    __syncthreads();
    if (tid < 128) {
        const float v = red[tid] + red[128 + tid] + red[256 + tid] + red[384 + tid];
        ws[YP_OFF + ((size_t)b*G2 + blockIdx.x)*128 + tid] = v;
    }
}

// ---------------- Kernel D1: parallel reduce of pass2 partials (one block per output) ----------------
__global__ __launch_bounds__(64) void prep2a_kernel(
    const float* __restrict__ ws_r, float* __restrict__ ws)
{
    const int o2 = blockIdx.x;            // [0,256): b = o2>>7, i = o2&127
    const int b = o2 >> 7, i = o2 & 127;
    const float* p = ws_r + YP_OFF + (size_t)b*G2*128 + i;
    double acc = 0.0;
    for (int g = threadIdx.x; g < G2; g += 64) acc += (double)p[(size_t)g*128];
#pragma unroll
    for (int s = 32; s; s >>= 1) acc += __shfl_down(acc, s, 64);
    if (threadIdx.x == 0) ((double*)(ws + YS_OFF))[o2] = acc;
}

// ---------------- Kernel D2: gn2 coeffs + fold into aw1/ab1 ----------------
__global__ void prep2b_kernel(const float* __restrict__ ws_r,
                              const float* __restrict__ g2, const float* __restrict__ be2,
                              const float* __restrict__ aw1, const float* __restrict__ ab1,
                              float* __restrict__ ws)
{
    __shared__ float EH[2][64], EQ[2][64];
    __shared__ float A2s[2][64];
    const int t = threadIdx.x;   // 256
    const double* YS = (const double*)(ws_r + YS_OFF);
    if (t < 128) {
        const int b = t >> 6, o = t & 63;
        const double invMK = 1.0 / (double)MK;
        const double my = YS[b*128 + o] * invMK;
        const double qy = YS[b*128 + 64 + o] * invMK;
        const double beff = (double)ws_r[BEFF_OFF + o];
        EH[b][o] = (float)(my + beff);
        EQ[b][o] = (float)(qy + 2.0*beff*my + beff*beff);
    }
    __syncthreads();
    if (t < 128) {
        const int b = t >> 6, o = t & 63, g = o & ~7;
        float mg = 0.f, qg = 0.f;
#pragma unroll
        for (int j = 0; j < 8; ++j) { mg += EH[b][g + j]; qg += EQ[b][g + j]; }
        mg *= 0.125f; qg *= 0.125f;
        const float var = fmaxf(qg - mg*mg, 0.f);
        const float a = g2[o] / sqrtf(var + GN_EPS);
        A2s[b][o] = a;
        ws[AB1P_OFF + b*64 + o] = fmaf(a, ab1[o], be2[o] - mg*a);
    }
    __syncthreads();
    _Float16* AW1P = (_Float16*)(ws + AW1P_OFF);
    for (int e = t; e < 8192; e += 256) {
        const int b = e >> 12, oc = e & 4095, o = oc >> 6;
        AW1P[e] = (_Float16)(A2s[b][o] * aw1[oc]);
    }
}

// ---------------- Kernel E: two-tile all-MFMA forward (64 pts/wave, B-fragments reused) ----------------
__global__ __launch_bounds__(256, 3) void pass3_kernel(
    const float* __restrict__ b2,
    const float* __restrict__ cws, float* __restrict__ out)
{
    __shared__ __align__(16) _Float16 Xs[8][32][72];   // [2*wv+t][row][col] 36.9 KB
    float* O = (float*)Xs;                             // aliased after barrier: [64][17]

    const int b = blockIdx.y;
    const int base = blockIdx.x * 256;                 // grid.x = 1563; last block partial
    const int tid = threadIdx.x;
    const int lane = tid & 63, wv = tid >> 6;
    const int colA = lane & 31;
    const int klo = (lane >> 5) * 8;

    const _Float16* xf   = (const _Float16*)(cws + XF_OFF);
    const _Float16* WF   = (const _Float16*)(cws + WF16_OFF);
    const _Float16* AW1P = (const _Float16*)(cws + AW1P_OFF) + (size_t)b*4096;
    const _Float16* W1F  = (const _Float16*)(cws + W1F_OFF);
    const unsigned short* m16 = (const unsigned short*)(cws + MSK_OFF) + (size_t)b*25024;

    int pt0[2];
    pt0[0] = base + 64*wv;
    pt0[1] = base + 64*wv + 32;
    unsigned mb[2];
#pragma unroll
    for (int t = 0; t < 2; ++t)
        mb[t] = (pt0[t] < MK) ? *(const unsigned*)(m16 + (pt0[t] >> 4)) : 0u;
    const unsigned mbs0 = __builtin_amdgcn_readfirstlane(mb[0]);
    const unsigned mbs1 = __builtin_amdgcn_readfirstlane(mb[1]);

    // ---- r1 via MFMA from cached x (both tiles; BX shared) ----
    {
        hf8 BX0, BX1;
        if (klo == 0) {
            BX0 = *(const hf8*)&W1F[(b*64 + 2*colA)*8];
            BX1 = *(const hf8*)&W1F[(b*64 + 2*colA + 1)*8];
        } else { BX0 = zero8(); BX1 = zero8(); }
        const float bias0 = cws[B1P_OFF + b*64 + 2*colA];
        const float bias1 = cws[B1P_OFF + b*64 + 2*colA + 1];
#pragma unroll
        for (int t = 0; t < 2; ++t) {
            hf8 ax = zero8();
            if (klo == 0 && pt0[t] < MK) {
                hf4 xv = *(const hf4*)&xf[((size_t)b*MK + pt0[t] + colA)*4];
#pragma unroll
                for (int j = 0; j < 4; ++j) ax[j] = xv[j];
            }
            f32x16 r0 = splat16(bias0), r1t = splat16(bias1);
            r0  = mfma16(ax, BX0, r0);
            r1t = mfma16(ax, BX1, r1t);
#pragma unroll
            for (int r = 0; r < 16; ++r) {
                const int row = ROWFN(r, lane);
                *(hf2*)&Xs[2*wv + t][row][2*colA] = pkrelu(pkcvt(r0[r], r1t[r]));
            }
            // mask bias into pad cols [64..71]: full 8-half write (no uninit LDS)
            if (lane < 32) {
                hf8 pad = zero8();
                pad[0] = ((mb[t] >> lane) & 1u) ? (_Float16)0.f : (_Float16)(-60000.f);
                *(hf8*)&Xs[2*wv + t][lane][64] = pad;
            }
        }
    }

    // ---- GEMM1: pe = r1 @ w2^T + b2 (B reused across tiles) ----
    hf2 pe_pk[2][16];   // packed pe kept for softmax (32 VGPRs)
    {
        f32x16 p00 = splat16(b2[2*colA]);
        f32x16 p01 = splat16(b2[2*colA + 1]);
        f32x16 p10 = p00, p11 = p01;
#pragma unroll
        for (int ks = 0; ks < 4; ++ks) {
            const int off = 16*ks + klo;
            hf8 a0  = *(const hf8*)&Xs[2*wv    ][colA][off];
            hf8 a1  = *(const hf8*)&Xs[2*wv + 1][colA][off];
            hf8 b0f = *(const hf8*)&WF[(2*colA)*64 + off];
            hf8 b1f = *(const hf8*)&WF[(2*colA + 1)*64 + off];
            p00 = mfma16(a0, b0f, p00);
            p01 = mfma16(a0, b1f, p01);
            p10 = mfma16(a1, b0f, p10);
            p11 = mfma16(a1, b1f, p11);
        }
#pragma unroll
        for (int r = 0; r < 16; ++r) {
            const int row = ROWFN(r, lane);
            pe_pk[0][r] = pkcvt(p00[r], p01[r]);
            pe_pk[1][r] = pkcvt(p10[r], p11[r]);
            *(hf2*)&Xs[2*wv    ][row][2*colA] = pe_pk[0][r];
            *(hf2*)&Xs[2*wv + 1][row][2*colA] = pe_pk[1][r];
        }
    }

    // ---- GEMM2: r2 = relu(pe @ (a2*aw1)^T + ab1') ----
    {
        f32x16 h00 = splat16(cws[AB1P_OFF + b*64 + 2*colA]);
        f32x16 h01 = splat16(cws[AB1P_OFF + b*64 + 2*colA + 1]);
        f32x16 h10 = h00, h11 = h01;
#pragma unroll
        for (int ks = 0; ks < 4; ++ks) {
            const int off = 16*ks + klo;
            hf8 a0  = *(const hf8*)&Xs[2*wv    ][colA][off];
            hf8 a1  = *(const hf8*)&Xs[2*wv + 1][colA][off];
            hf8 b0f = *(const hf8*)&AW1P[(2*colA)*64 + off];
            hf8 b1f = *(const hf8*)&AW1P[(2*colA + 1)*64 + off];
            h00 = mfma16(a0, b0f, h00);
            h01 = mfma16(a0, b1f, h01);
            h10 = mfma16(a1, b0f, h10);
            h11 = mfma16(a1, b1f, h11);
        }
#pragma unroll
        for (int r = 0; r < 16; ++r) {
            const int row = ROWFN(r, lane);
            *(hf2*)&Xs[2*wv    ][row][2*colA] = pkrelu(pkcvt(h00[r], h01[r]));
            *(hf2*)&Xs[2*wv + 1][row][2*colA] = pkrelu(pkcvt(h10[r], h11[r]));
        }
    }

    // ---- GEMM3: logits(log2) = r2 @ (aw2*log2e)^T + ab2*log2e + mask rank-1 ----
    f32x16 l00 = splat16(cws[AB2L_OFF + 2*colA]);
    f32x16 l01 = splat16(cws[AB2L_OFF + 2*colA + 1]);
    f32x16 l10 = l00, l11 = l01;
#pragma unroll
    for (int ks = 0; ks < 4; ++ks) {
        const int off = 16*ks + klo;
        hf8 a0  = *(const hf8*)&Xs[2*wv    ][colA][off];
        hf8 a1  = *(const hf8*)&Xs[2*wv + 1][colA][off];
        hf8 b0f = *(const hf8*)&WF[4096 + (2*colA)*64 + off];
        hf8 b1f = *(const hf8*)&WF[4096 + (2*colA + 1)*64 + off];
        l00 = mfma16(a0, b0f, l00);
        l01 = mfma16(a0, b1f, l01);
        l10 = mfma16(a1, b0f, l10);
        l11 = mfma16(a1, b1f, l11);
    }
    {
        hf8 b5 = zero8();
        if (klo == 0) b5[0] = (_Float16)1.f;
        hf8 a50 = zero8(), a51 = zero8();
        if (klo == 0) {
            a50 = *(const hf8*)&Xs[2*wv    ][colA][64];
            a51 = *(const hf8*)&Xs[2*wv + 1][colA][64];
        }
        l00 = mfma16(a50, b5, l00);
        l01 = mfma16(a50, b5, l01);
        l10 = mfma16(a51, b5, l10);
        l11 = mfma16(a51, b5, l11);
    }

    __syncthreads();   // all Xs reads done; O may alias Xs

    // ---- softmax over K=16 (exp2 domain) + weighted pe sum ----
    {
        auto softmax_tile = [&](const f32x16& lg, const hf2* pp, unsigned mbst,
                                int t, int j) {
#pragma unroll
            for (int mh = 0; mh < 2; ++mh) {
                float mx = lg[8*mh];
#pragma unroll
                for (int rr = 1; rr < 8; ++rr) mx = fmaxf(mx, lg[8*mh + rr]);
                mx = fmaxf(mx, __shfl_xor(mx, 32, 64));
                float se, sw = 0.f;
                if (((mbst >> (16*mh)) & 0xFFFFu) != 0u) {
                    se = 0.f;
#pragma unroll
                    for (int rr = 0; rr < 8; ++rr) {
                        const float e = exp2f(lg[8*mh + rr] - mx);
                        se += e;
                        sw = fmaf(e, (float)pp[8*mh + rr][j], sw);
                    }
                } else {
                    se = 8.f;
#pragma unroll
                    for (int rr = 0; rr < 8; ++rr) sw += (float)pp[8*mh + rr][j];
                }
                se += __shfl_xor(se, 32, 64);
                sw += __shfl_xor(sw, 32, 64);
                if (lane < 32)
                    O[(2*lane + j)*17 + (4*wv + 2*t + mh)] = sw * __builtin_amdgcn_rcpf(se);
            }
        };
        softmax_tile(l00, pe_pk[0], mbs0, 0, 0);
        softmax_tile(l01, pe_pk[0], mbs0, 0, 1);
        softmax_tile(l10, pe_pk[1], mbs1, 1, 0);
        softmax_tile(l11, pe_pk[1], mbs1, 1, 1);
    }
    __syncthreads();

    {   // 64 ch x 16 m per block, one float4 per thread
        const int o = tid >> 2, mq = (tid & 3) * 4;
        const int m0 = blockIdx.x * 16;
        if (m0 + mq < Mn) {
            float4 v;
            v.x = O[o*17 + mq];     v.y = O[o*17 + mq + 1];
            v.z = O[o*17 + mq + 2]; v.w = O[o*17 + mq + 3];
            *(float4*)&out[((size_t)b*64 + o)*Mn + m0 + mq] = v;
        }
    }
}

extern "C" void kernel_launch(void* const* d_in, const int* in_sizes, int n_in,
                              void* d_out, int out_size, void* d_ws, size_t ws_size,
                              hipStream_t stream) {
    (void)in_sizes; (void)n_in; (void)out_size; (void)ws_size;
    const float* q    = (const float*)d_in[0];
    const float* kx   = (const float*)d_in[1];
    const int*   idx  = (const int*)  d_in[2];
    const int*   mask = (const int*)  d_in[3];
    const float* w1   = (const float*)d_in[4];
    const float* b1   = (const float*)d_in[5];
    const float* g1   = (const float*)d_in[6];
    const float* be1  = (const float*)d_in[7];
    const float* w2   = (const float*)d_in[8];
    const float* b2   = (const float*)d_in[9];
    const float* aw1  = (const float*)d_in[10];
    const float* ab1  = (const float*)d_in[11];
    const float* g2   = (const float*)d_in[12];
    const float* be2  = (const float*)d_in[13];
    const float* aw2  = (const float*)d_in[14];
    const float* ab2  = (const float*)d_in[15];
    float* out = (float*)d_out;
    float* ws  = (float*)d_ws;

    prep0_kernel<<<256, 256, 0, stream>>>(q, kx, ws);
    gatherx_kernel<<<dim3(G1, Bn), 256, 0, stream>>>(idx, mask, ws);
    prep1_kernel<<<17, 256, 0, stream>>>(ws, w1, b1, g1, be1, w2, b2, aw1, ab1, aw2, ab2, ws);
    pass2_kernel<<<dim3(G2, Bn), 256, 0, stream>>>(ws, ws);
    prep2a_kernel<<<256, 64, 0, stream>>>(ws, ws);
    prep2b_kernel<<<1, 256, 0, stream>>>(ws, g2, be2, aw1, ab1, ws);
    pass3_kernel<<<dim3((MK + 255)/256, Bn), 256, 0, stream>>>(b2, ws, out);
}

// Round 13
// 194.969 us; speedup vs baseline: 1.0679x; 1.0132x over previous
//
#include <hip/hip_runtime.h>

// Problem constants
#define Bn 2
#define Mn 25000
#define Nn 100000
#define MK 400000           // Mn*Kn points per batch
#define GN_EPS 1e-5f
#define NEG_BIG (-3.402823466e+38f)
#define LOG2E 1.44269504088896340736f

#define G1 512              // gatherx blocks per batch
#define G2 512              // pass2 blocks per batch

// ws layout (float offsets). No atomics; every region fully written before read.
#define BEFF_OFF 0        // [64]      at_w1@pe_b2 + at_b1
#define B1P_OFF  64       // [2][64]   folded gn1 bias
#define AB1P_OFF 192      // [2][64]   folded gn2 bias: a2*ab1 + c2
#define AB2L_OFF 320      // [64]      ab2 * log2e
#define WF16_OFF 384      // 3*4096 f16: w2, aw2*log2e, Weff    (6144 floats)
#define AW1P_OFF 6528     // [2][4096] f16 folded a2*aw1        (4096 floats)
#define W1F_OFF  10624    // [2][64][8] f16 a1-folded W1, K-pad (512 floats)
#define MSK_OFF  11136    // [2][25024] u16 packed mask         (25024 floats)
#define SP_OFF   36160    // [2][G1][16] gatherx moment partials(16384 floats)
#define YP_OFF   52544    // [2][G2][128] pass2 partials        (131072 floats)
#define YS_OFF   183616   // [2][128] doubles: reduced sums     (512 floats)
#define KXT_OFF  184128   // [2][Nn][4] f32 transposed kx       (800000 floats)
#define QT_OFF   984128   // [2][Mn][4] f32 transposed q        (200000 floats)
#define XF_OFF   1184128  // [2][MK][4] f16 cached local_pattern(1600000 floats)
// total: 2784128 floats ≈ 11.14 MB

typedef _Float16 hf8 __attribute__((ext_vector_type(8)));
typedef _Float16 hf4 __attribute__((ext_vector_type(4)));
typedef _Float16 hf2 __attribute__((ext_vector_type(2)));
typedef float f32x16 __attribute__((ext_vector_type(16)));

__device__ __forceinline__ f32x16 mfma16(hf8 a, hf8 b, f32x16 c) {
    return __builtin_amdgcn_mfma_f32_32x32x16_f16(a, b, c, 0, 0, 0);
}
__device__ __forceinline__ f32x16 splat16(float v) {
    f32x16 x;
#pragma unroll
    for (int r = 0; r < 16; ++r) x[r] = v;
    return x;
}
__device__ __forceinline__ hf8 zero8() {
    hf8 z;
#pragma unroll
    for (int j = 0; j < 8; ++j) z[j] = (_Float16)0.f;
    return z;
}
__device__ __forceinline__ hf2 pkcvt(float a, float b) {
    return __builtin_bit_cast(hf2, __builtin_amdgcn_cvt_pkrtz(a, b));
}
__device__ __forceinline__ hf2 pkrelu(hf2 v) {
    hf2 z; z[0] = (_Float16)0.f; z[1] = (_Float16)0.f;
    return __builtin_elementwise_max(v, z);
}
__device__ __forceinline__ float waveSum(float v) {
#pragma unroll
    for (int s = 32; s; s >>= 1) v += __shfl_down(v, s, 64);
    return v;
}
#define ROWFN(r, lane) (((r) & 3) + 8*((r) >> 2) + 4*((lane) >> 5))

// ---------------- Kernel 0: transpose kx/q to [n][4] ----------------
__global__ __launch_bounds__(256) void prep0_kernel(
    const float* __restrict__ q, const float* __restrict__ kx,
    float* __restrict__ ws)
{
    float4* kxt = (float4*)(ws + KXT_OFF);
    float4* qt  = (float4*)(ws + QT_OFF);
    for (int e = blockIdx.x*256 + threadIdx.x; e < 2*Nn; e += gridDim.x*256) {
        const int b = e / Nn, n = e % Nn;
        float4 v;
        v.x = kx[(b*3+0)*Nn + n]; v.y = kx[(b*3+1)*Nn + n];
        v.z = kx[(b*3+2)*Nn + n]; v.w = 0.f;
        kxt[e] = v;
    }
    for (int e = blockIdx.x*256 + threadIdx.x; e < 2*Mn; e += gridDim.x*256) {
        const int b = e / Mn, m = e % Mn;
        float4 v;
        v.x = q[(b*3+0)*Mn + m]; v.y = q[(b*3+1)*Mn + m];
        v.z = q[(b*3+2)*Mn + m]; v.w = 0.f;
        qt[e] = v;
    }
}

// ---------------- Kernel A: gather once -> x-cache (f16) + packed mask + moments ----------------
__global__ __launch_bounds__(256) void gatherx_kernel(
    const int* __restrict__ idx, const int* __restrict__ mask,
    float* __restrict__ ws)
{
    __shared__ float red[4][16];
    const int b = blockIdx.y;
    const float4* kxt = (const float4*)(ws + KXT_OFF) + (size_t)b*Nn;
    const float4* qt  = (const float4*)(ws + QT_OFF)  + (size_t)b*Mn;
    _Float16* xf = (_Float16*)(ws + XF_OFF);
    unsigned short* m16 = (unsigned short*)(ws + MSK_OFF) + (size_t)b*25024;
    float v[14];
#pragma unroll
    for (int j = 0; j < 14; ++j) v[j] = 0.f;

    for (int i = blockIdx.x*256 + threadIdx.x; i < MK; i += G1*256) {
        const int mm = i >> 4;
        const int id = idx[(size_t)b*MK + i];
        const float4 kv = kxt[id];
        const float4 qv = qt[mm];
        const float ox = kv.x - qv.x, oy = kv.y - qv.y, oz = kv.z - qv.z;
        const float d  = sqrtf(ox*ox + oy*oy + oz*oz);
        const float inv = 1.0f / fmaxf(d, 1e-12f);
        const float x0 = ox*inv, x1 = oy*inv, x2 = oz*inv, x3 = d;

        const hf2 lo = pkcvt(x0, x1);
        const hf2 hi = pkcvt(x2, x3);
        hf4 pk;
        pk[0] = lo[0]; pk[1] = lo[1]; pk[2] = hi[0]; pk[3] = hi[1];
        *(hf4*)&xf[((size_t)b*MK + i)*4] = pk;

        const unsigned long long mb = __ballot(mask[(size_t)b*MK + i] != 0);
        if ((threadIdx.x & 63) == 0)
            *(unsigned long long*)&m16[i >> 4] = mb;

        v[0] += x0; v[1] += x1; v[2] += x2; v[3] += x3;
        v[4] += x0*x0; v[5] += x0*x1; v[6] += x0*x2; v[7] += x0*x3;
        v[8] += x1*x1; v[9] += x1*x2; v[10] += x1*x3;
        v[11] += x2*x2; v[12] += x2*x3; v[13] += x3*x3;
    }
    const int lane = threadIdx.x & 63, wv = threadIdx.x >> 6;
#pragma unroll
    for (int j = 0; j < 14; ++j) v[j] = waveSum(v[j]);
    if (lane == 0) {
#pragma unroll
        for (int j = 0; j < 14; ++j) red[wv][j] = v[j];
    }
    __syncthreads();
    if (threadIdx.x < 14)
        ws[SP_OFF + ((size_t)b*G1 + blockIdx.x)*16 + threadIdx.x] =
            red[0][threadIdx.x] + red[1][threadIdx.x] + red[2][threadIdx.x] + red[3][threadIdx.x];
}

// ---------------- Kernel B: block0: moments -> gn1 fold + beff + ab2 prescale;
//                  blocks 1..16: Weff + f16 weight conversion (data-independent) ----------------
__global__ void prep1_kernel(
    const float* __restrict__ ws_r,
    const float* __restrict__ w1, const float* __restrict__ b1,
    const float* __restrict__ g1, const float* __restrict__ be1,
    const float* __restrict__ w2, const float* __restrict__ pe_b2,
    const float* __restrict__ aw1, const float* __restrict__ ab1,
    const float* __restrict__ aw2, const float* __restrict__ ab2,
    float* __restrict__ ws)
{
    const int t = threadIdx.x;
    _Float16* WF = (_Float16*)(ws + WF16_OFF);

    if (blockIdx.x > 0) {
        const int e = (blockIdx.x - 1)*256 + t;
        const int o = e >> 6, c = e & 63;
        WF[e]        = (_Float16)w2[e];
        WF[4096 + e] = (_Float16)(aw2[e] * LOG2E);
        float acc = 0.f;
        for (int d = 0; d < 64; ++d) acc = fmaf(aw1[o*64 + d], w2[d*64 + c], acc);
        WF[8192 + e] = (_Float16)acc;
        return;
    }

    __shared__ double S[2][14];
    __shared__ float Eh[2][64], Eq[2][64];

    if (t < 28) {
        const int b = t / 14, j = t % 14;
        const float* p = ws_r + SP_OFF + (size_t)b*G1*16 + j;
        double acc = 0.0;
        for (int g = 0; g < G1; g += 4)
            acc += (double)p[(g+0)*16] + (double)p[(g+1)*16]
                 + (double)p[(g+2)*16] + (double)p[(g+3)*16];
        S[b][j] = acc;
    }
    __syncthreads();

    if (t < 128) {
        const int b = t >> 6, o = t & 63;
        const double inv = 1.0 / (double)MK;
        double mu[4];
#pragma unroll
        for (int c = 0; c < 4; ++c) mu[c] = S[b][c] * inv;
        double m2[4][4];
        {
            const int map[4][4] = {{0,1,2,3},{1,4,5,6},{2,5,7,8},{3,6,8,9}};
#pragma unroll
            for (int c = 0; c < 4; ++c)
#pragma unroll
                for (int c2 = 0; c2 < 4; ++c2)
                    m2[c][c2] = S[b][4 + map[c][c2]] * inv;
        }
        double w[4];
#pragma unroll
        for (int c = 0; c < 4; ++c) w[c] = (double)w1[o*4 + c];
        double s = 0.0, qd = 0.0;
#pragma unroll
        for (int c = 0; c < 4; ++c) {
            s += w[c] * mu[c];
#pragma unroll
            for (int c2 = 0; c2 < 4; ++c2) qd += w[c]*w[c2]*m2[c][c2];
        }
        const double bb = (double)b1[o];
        Eh[b][o] = (float)(s + bb);
        Eq[b][o] = (float)(qd + 2.0*bb*s + bb*bb);
    }
    __syncthreads();
    if (t < 128) {
        const int b = t >> 6, o = t & 63, g = o & ~7;
        float mg = 0.f, qg = 0.f;
#pragma unroll
        for (int j = 0; j < 8; ++j) { mg += Eh[b][g + j]; qg += Eq[b][g + j]; }
        mg *= 0.125f; qg *= 0.125f;
        const float var = fmaxf(qg - mg*mg, 0.f);
        const float a = g1[o] / sqrtf(var + GN_EPS);
        const float c1v = be1[o] - mg*a;
        _Float16* W1F = (_Float16*)(ws + W1F_OFF);
        hf8 wrow;
#pragma unroll
        for (int c = 0; c < 4; ++c) wrow[c] = (_Float16)(a * w1[o*4 + c]);
#pragma unroll
        for (int c = 4; c < 8; ++c) wrow[c] = (_Float16)0.f;
        *(hf8*)&W1F[(b*64 + o)*8] = wrow;
        ws[B1P_OFF + b*64 + o] = fmaf(a, b1[o], c1v);
    }
    if (t < 64) {
        float acc = ab1[t];
        for (int d = 0; d < 64; ++d) acc = fmaf(aw1[t*64 + d], pe_b2[d], acc);
        ws[BEFF_OFF + t] = acc;
    } else if (t < 128) {
        ws[AB2L_OFF + (t - 64)] = ab2[t - 64] * LOG2E;
    }
}

// ---------------- Kernel C: Σy, Σy² (y = Weff@r1), all-MFMA (R10 version) ----------------
__global__ __launch_bounds__(256, 4) void pass2_kernel(
    const float* __restrict__ cws, float* __restrict__ ws)
{
    __shared__ __align__(16) _Float16 Xs[4][32][72];
    const int b = blockIdx.y;
    const int tid = threadIdx.x, lane = tid & 63, wv = tid >> 6;
    const int colA = lane & 31;
    const int klo = (lane >> 5) * 8;
    const _Float16* xf  = (const _Float16*)(cws + XF_OFF);
    const _Float16* WFe = (const _Float16*)(cws + WF16_OFF) + 8192;  // Weff
    const _Float16* W1F = (const _Float16*)(cws + W1F_OFF);

    hf8 BW[2][4];
#pragma unroll
    for (int jc = 0; jc < 2; ++jc)
#pragma unroll
        for (int ks = 0; ks < 4; ++ks)
            BW[jc][ks] = *(const hf8*)&WFe[(2*colA + jc)*64 + 16*ks + klo];
    hf8 BX[2];
    if (klo == 0) {
        BX[0] = *(const hf8*)&W1F[(b*64 + 2*colA)*8];
        BX[1] = *(const hf8*)&W1F[(b*64 + 2*colA + 1)*8];
    } else { BX[0] = zero8(); BX[1] = zero8(); }
    const float bias0 = cws[B1P_OFF + b*64 + 2*colA];
    const float bias1 = cws[B1P_OFF + b*64 + 2*colA + 1];

    float sh[2] = {0.f, 0.f}, sq[2] = {0.f, 0.f};

    for (int base = blockIdx.x * 128; base < MK; base += G2 * 128) {
        const int pt0 = base + 32*wv;
        hf8 ax = zero8();
        if (klo == 0) {
            hf4 xv = *(const hf4*)&xf[((size_t)b*MK + pt0 + colA)*4];
#pragma unroll
            for (int j = 0; j < 4; ++j) ax[j] = xv[j];
        }
        f32x16 r0 = splat16(bias0), r1t = splat16(bias1);
        r0  = mfma16(ax, BX[0], r0);
        r1t = mfma16(ax, BX[1], r1t);
#pragma unroll
        for (int r = 0; r < 16; ++r) {
            const int row = ROWFN(r, lane);
            *(hf2*)&Xs[wv][row][2*colA] = pkrelu(pkcvt(r0[r], r1t[r]));
        }
        hf8 A[4];
#pragma unroll
        for (int ks = 0; ks < 4; ++ks)
            A[ks] = *(const hf8*)&Xs[wv][colA][16*ks + klo];
#pragma unroll
        for (int jc = 0; jc < 2; ++jc) {
            f32x16 C = splat16(0.f);
#pragma unroll
            for (int ks = 0; ks < 4; ++ks) C = mfma16(A[ks], BW[jc][ks], C);
#pragma unroll
            for (int r = 0; r < 16; ++r) {
                const float vy = C[r];
                sh[jc] += vy;
                sq[jc] = fmaf(vy, vy, sq[jc]);
            }
        }
    }

#pragma unroll
    for (int jc = 0; jc < 2; ++jc) {
        sh[jc] += __shfl_xor(sh[jc], 32, 64);
        sq[jc] += __shfl_xor(sq[jc], 32, 64);
    }
    __syncthreads();
    float* red = (float*)Xs;   // [4][128]
    if (lane < 32) {
#pragma unroll
        for (int jc = 0; jc < 2; ++jc) {
            red[wv*128 +      2*colA + jc] = sh[jc];
            red[wv*128 + 64 + 2*colA + jc] = sq[jc];
        }
    }
    __syncthreads();
    if (tid < 128) {
        const float v = red[tid] + red[128 + tid] + red[256 + tid] + red[384 + tid];
        ws[YP_OFF + ((size_t)b*G2 + blockIdx.x)*128 + tid] = v;
    }
}

// ---------------- Kernel D1: parallel reduce of pass2 partials (one block per output) ----------------
__global__ __launch_bounds__(64) void prep2a_kernel(
    const float* __restrict__ ws_r, float* __restrict__ ws)
{
    const int o2 = blockIdx.x;            // [0,256): b = o2>>7, i = o2&127
    const int b = o2 >> 7, i = o2 & 127;
    const float* p = ws_r + YP_OFF + (size_t)b*G2*128 + i;
    double acc = 0.0;
    for (int g = threadIdx.x; g < G2; g += 64) acc += (double)p[(size_t)g*128];
#pragma unroll
    for (int s = 32; s; s >>= 1) acc += __shfl_down(acc, s, 64);
    if (threadIdx.x == 0) ((double*)(ws + YS_OFF))[o2] = acc;
}

// ---------------- Kernel D2: gn2 coeffs + fold into aw1/ab1 ----------------
__global__ void prep2b_kernel(const float* __restrict__ ws_r,
                              const float* __restrict__ g2, const float* __restrict__ be2,
                              const float* __restrict__ aw1, const float* __restrict__ ab1,
                              float* __restrict__ ws)
{
    __shared__ float EH[2][64], EQ[2][64];
    __shared__ float A2s[2][64];
    const int t = threadIdx.x;   // 256
    const double* YS = (const double*)(ws_r + YS_OFF);
    if (t < 128) {
        const int b = t >> 6, o = t & 63;
        const double invMK = 1.0 / (double)MK;
        const double my = YS[b*128 + o] * invMK;
        const double qy = YS[b*128 + 64 + o] * invMK;
        const double beff = (double)ws_r[BEFF_OFF + o];
        EH[b][o] = (float)(my + beff);
        EQ[b][o] = (float)(qy + 2.0*beff*my + beff*beff);
    }
    __syncthreads();
    if (t < 128) {
        const int b = t >> 6, o = t & 63, g = o & ~7;
        float mg = 0.f, qg = 0.f;
#pragma unroll
        for (int j = 0; j < 8; ++j) { mg += EH[b][g + j]; qg += EQ[b][g + j]; }
        mg *= 0.125f; qg *= 0.125f;
        const float var = fmaxf(qg - mg*mg, 0.f);
        const float a = g2[o] / sqrtf(var + GN_EPS);
        A2s[b][o] = a;
        ws[AB1P_OFF + b*64 + o] = fmaf(a, ab1[o], be2[o] - mg*a);
    }
    __syncthreads();
    _Float16* AW1P = (_Float16*)(ws + AW1P_OFF);
    for (int e = t; e < 8192; e += 256) {
        const int b = e >> 12, oc = e & 4095, o = oc >> 6;
        AW1P[e] = (_Float16)(A2s[b][o] * aw1[oc]);
    }
}

// ---------------- Kernel E: two-tile all-MFMA forward (64 pts/wave, B-fragments reused) ----------------
__global__ __launch_bounds__(256, 3) void pass3_kernel(
    const float* __restrict__ b2,
    const float* __restrict__ cws, float* __restrict__ out)
{
    __shared__ __align__(16) _Float16 Xs[8][32][72];   // [2*wv+t][row][col] 36.9 KB
    float* O = (float*)Xs;                             // aliased after barrier: [64][17]

    const int b = blockIdx.y;
    const int base = blockIdx.x * 256;                 // grid.x = 1563; last block partial
    const int tid = threadIdx.x;
    const int lane = tid & 63, wv = tid >> 6;
    const int colA = lane & 31;
    const int klo = (lane >> 5) * 8;

    const _Float16* xf   = (const _Float16*)(cws + XF_OFF);
    const _Float16* WF   = (const _Float16*)(cws + WF16_OFF);
    const _Float16* AW1P = (const _Float16*)(cws + AW1P_OFF) + (size_t)b*4096;
    const _Float16* W1F  = (const _Float16*)(cws + W1F_OFF);
    const unsigned short* m16 = (const unsigned short*)(cws + MSK_OFF) + (size_t)b*25024;

    int pt0[2];
    pt0[0] = base + 64*wv;
    pt0[1] = base + 64*wv + 32;
    unsigned mb[2];
#pragma unroll
    for (int t = 0; t < 2; ++t)
        mb[t] = (pt0[t] < MK) ? *(const unsigned*)(m16 + (pt0[t] >> 4)) : 0u;
    const unsigned mbs0 = __builtin_amdgcn_readfirstlane(mb[0]);
    const unsigned mbs1 = __builtin_amdgcn_readfirstlane(mb[1]);

    // ---- r1 via MFMA from cached x (both tiles; BX shared) ----
    {
        hf8 BX0, BX1;
        if (klo == 0) {
            BX0 = *(const hf8*)&W1F[(b*64 + 2*colA)*8];
            BX1 = *(const hf8*)&W1F[(b*64 + 2*colA + 1)*8];
        } else { BX0 = zero8(); BX1 = zero8(); }
        const float bias0 = cws[B1P_OFF + b*64 + 2*colA];
        const float bias1 = cws[B1P_OFF + b*64 + 2*colA + 1];
#pragma unroll
        for (int t = 0; t < 2; ++t) {
            hf8 ax = zero8();
            if (klo == 0 && pt0[t] < MK) {
                hf4 xv = *(const hf4*)&xf[((size_t)b*MK + pt0[t] + colA)*4];
#pragma unroll
                for (int j = 0; j < 4; ++j) ax[j] = xv[j];
            }
            f32x16 r0 = splat16(bias0), r1t = splat16(bias1);
            r0  = mfma16(ax, BX0, r0);
            r1t = mfma16(ax, BX1, r1t);
#pragma unroll
            for (int r = 0; r < 16; ++r) {
                const int row = ROWFN(r, lane);
                *(hf2*)&Xs[2*wv + t][row][2*colA] = pkrelu(pkcvt(r0[r], r1t[r]));
            }
            // mask bias into pad cols [64..71]: full 8-half write (no uninit LDS)
            if (lane < 32) {
                hf8 pad = zero8();
                pad[0] = ((mb[t] >> lane) & 1u) ? (_Float16)0.f : (_Float16)(-60000.f);
                *(hf8*)&Xs[2*wv + t][lane][64] = pad;
            }
        }
    }

    // ---- GEMM1: pe = r1 @ w2^T + b2 (B reused across tiles) ----
    hf2 pe_pk[2][16];   // packed pe kept for softmax (32 VGPRs)
    {
        f32x16 p00 = splat16(b2[2*colA]);
        f32x16 p01 = splat16(b2[2*colA + 1]);
        f32x16 p10 = p00, p11 = p01;
#pragma unroll
        for (int ks = 0; ks < 4; ++ks) {
            const int off = 16*ks + klo;
            hf8 a0  = *(const hf8*)&Xs[2*wv    ][colA][off];
            hf8 a1  = *(const hf8*)&Xs[2*wv + 1][colA][off];
            hf8 b0f = *(const hf8*)&WF[(2*colA)*64 + off];
            hf8 b1f = *(const hf8*)&WF[(2*colA + 1)*64 + off];
            p00 = mfma16(a0, b0f, p00);
            p01 = mfma16(a0, b1f, p01);
            p10 = mfma16(a1, b0f, p10);
            p11 = mfma16(a1, b1f, p11);
        }
#pragma unroll
        for (int r = 0; r < 16; ++r) {
            const int row = ROWFN(r, lane);
            pe_pk[0][r] = pkcvt(p00[r], p01[r]);
            pe_pk[1][r] = pkcvt(p10[r], p11[r]);
            *(hf2*)&Xs[2*wv    ][row][2*colA] = pe_pk[0][r];
            *(hf2*)&Xs[2*wv + 1][row][2*colA] = pe_pk[1][r];
        }
    }

    // ---- GEMM2: r2 = relu(pe @ (a2*aw1)^T + ab1') ----
    {
        f32x16 h00 = splat16(cws[AB1P_OFF + b*64 + 2*colA]);
        f32x16 h01 = splat16(cws[AB1P_OFF + b*64 + 2*colA + 1]);
        f32x16 h10 = h00, h11 = h01;
#pragma unroll
        for (int ks = 0; ks < 4; ++ks) {
            const int off = 16*ks + klo;
            hf8 a0  = *(const hf8*)&Xs[2*wv    ][colA][off];
            hf8 a1  = *(const hf8*)&Xs[2*wv + 1][colA][off];
            hf8 b0f = *(const hf8*)&AW1P[(2*colA)*64 + off];
            hf8 b1f = *(const hf8*)&AW1P[(2*colA + 1)*64 + off];
            h00 = mfma16(a0, b0f, h00);
            h01 = mfma16(a0, b1f, h01);
            h10 = mfma16(a1, b0f, h10);
            h11 = mfma16(a1, b1f, h11);
        }
#pragma unroll
        for (int r = 0; r < 16; ++r) {
            const int row = ROWFN(r, lane);
            *(hf2*)&Xs[2*wv    ][row][2*colA] = pkrelu(pkcvt(h00[r], h01[r]));
            *(hf2*)&Xs[2*wv + 1][row][2*colA] = pkrelu(pkcvt(h10[r], h11[r]));
        }
    }

    // ---- GEMM3: logits(log2) = r2 @ (aw2*log2e)^T + ab2*log2e + mask rank-1 ----
    f32x16 l00 = splat16(cws[AB2L_OFF + 2*colA]);
    f32x16 l01 = splat16(cws[AB2L_OFF + 2*colA + 1]);
    f32x16 l10 = l00, l11 = l01;
#pragma unroll
    for (int ks = 0; ks < 4; ++ks) {
        const int off = 16*ks + klo;
        hf8 a0  = *(const hf8*)&Xs[2*wv    ][colA][off];
        hf8 a1  = *(const hf8*)&Xs[2*wv + 1][colA][off];
        hf8 b0f = *(const hf8*)&WF[4096 + (2*colA)*64 + off];
        hf8 b1f = *(const hf8*)&WF[4096 + (2*colA + 1)*64 + off];
        l00 = mfma16(a0, b0f, l00);
        l01 = mfma16(a0, b1f, l01);
        l10 = mfma16(a1, b0f, l10);
        l11 = mfma16(a1, b1f, l11);
    }
    {
        hf8 b5 = zero8();
        if (klo == 0) b5[0] = (_Float16)1.f;
        hf8 a50 = zero8(), a51 = zero8();
        if (klo == 0) {
            a50 = *(const hf8*)&Xs[2*wv    ][colA][64];
            a51 = *(const hf8*)&Xs[2*wv + 1][colA][64];
        }
        l00 = mfma16(a50, b5, l00);
        l01 = mfma16(a50, b5, l01);
        l10 = mfma16(a51, b5, l10);
        l11 = mfma16(a51, b5, l11);
    }

    __syncthreads();   // all Xs reads done; O may alias Xs

    // ---- softmax over K=16 (exp2 domain) + weighted pe sum ----
    {
        auto softmax_tile = [&](const f32x16& lg, const hf2* pp, unsigned mbst,
                                int t, int j) {
#pragma unroll
            for (int mh = 0; mh < 2; ++mh) {
                float mx = lg[8*mh];
#pragma unroll
                for (int rr = 1; rr < 8; ++rr) mx = fmaxf(mx, lg[8*mh + rr]);
                mx = fmaxf(mx, __shfl_xor(mx, 32, 64));
                float se, sw = 0.f;
                if (((mbst >> (16*mh)) & 0xFFFFu) != 0u) {
                    se = 0.f;
#pragma unroll
                    for (int rr = 0; rr < 8; ++rr) {
                        const float e = exp2f(lg[8*mh + rr] - mx);
                        se += e;
                        sw = fmaf(e, (float)pp[8*mh + rr][j], sw);
                    }
                } else {
                    se = 8.f;
#pragma unroll
                    for (int rr = 0; rr < 8; ++rr) sw += (float)pp[8*mh + rr][j];
                }
                se += __shfl_xor(se, 32, 64);
                sw += __shfl_xor(sw, 32, 64);
                if (lane < 32)
                    O[(2*lane + j)*17 + (4*wv + 2*t + mh)] = sw * __builtin_amdgcn_rcpf(se);
            }
        };
        softmax_tile(l00, pe_pk[0], mbs0, 0, 0);
        softmax_tile(l01, pe_pk[0], mbs0, 0, 1);
        softmax_tile(l10, pe_pk[1], mbs1, 1, 0);
        softmax_tile(l11, pe_pk[1], mbs1, 1, 1);
    }
    __syncthreads();

    {   // 64 ch x 16 m per block, one float4 per thread
        const int o = tid >> 2, mq = (tid & 3) * 4;
        const int m0 = blockIdx.x * 16;
        if (m0 + mq < Mn) {
            float4 v;
            v.x = O[o*17 + mq];     v.y = O[o*17 + mq + 1];
            v.z = O[o*17 + mq + 2]; v.w = O[o*17 + mq + 3];
            *(float4*)&out[((size_t)b*64 + o)*Mn + m0 + mq] = v;
        }
    }
}

extern "C" void kernel_launch(void* const* d_in, const int* in_sizes, int n_in,
                              void* d_out, int out_size, void* d_ws, size_t ws_size,
                              hipStream_t stream) {
    (void)in_sizes; (void)n_in; (void)out_size; (void)ws_size;
    const float* q    = (const float*)d_in[0];
    const float* kx   = (const float*)d_in[1];
    const int*   idx  = (const int*)  d_in[2];
    const int*   mask = (const int*)  d_in[3];
    const float* w1   = (const float*)d_in[4];
    const float* b1   = (const float*)d_in[5];
    const float* g1   = (const float*)d_in[6];
    const float* be1  = (const float*)d_in[7];
    const float* w2   = (const float*)d_in[8];
    const float* b2   = (const float*)d_in[9];
    const float* aw1  = (const float*)d_in[10];
    const float* ab1  = (const float*)d_in[11];
    const float* g2   = (const float*)d_in[12];
    const float* be2  = (const float*)d_in[13];
    const float* aw2  = (const float*)d_in[14];
    const float* ab2  = (const float*)d_in[15];
    float* out = (float*)d_out;
    float* ws  = (float*)d_ws;

    prep0_kernel<<<256, 256, 0, stream>>>(q, kx, ws);
    gatherx_kernel<<<dim3(G1, Bn), 256, 0, stream>>>(idx, mask, ws);
    prep1_kernel<<<17, 256, 0, stream>>>(ws, w1, b1, g1, be1, w2, b2, aw1, ab1, aw2, ab2, ws);
    pass2_kernel<<<dim3(G2, Bn), 256, 0, stream>>>(ws, ws);
    prep2a_kernel<<<256, 64, 0, stream>>>(ws, ws);
    prep2b_kernel<<<1, 256, 0, stream>>>(ws, g2, be2, aw1, ab1, ws);
    pass3_kernel<<<dim3((MK + 255)/256, Bn), 256, 0, stream>>>(b2, ws, out);
}